// Round 11
// baseline (126.322 us; speedup 1.0000x reference)
//
#include <hip/hip_runtime.h>
#include <hip/hip_bf16.h>
#include <math.h>

#define BB 2
#define TT 2048
#define CCH 1024
#define HH 16
#define DD 64
#define BT (BB*TT)     // 4096
#define N3 (3*CCH)     // 3072

typedef __attribute__((ext_vector_type(8))) short short8;
typedef __attribute__((ext_vector_type(4))) float f32x4;
typedef __attribute__((ext_vector_type(16))) float f32x16;

__device__ __forceinline__ unsigned short f2bf(float f) {
  unsigned int u = __float_as_uint(f);
  unsigned int r = (u + 0x7FFFu + ((u >> 16) & 1u)) >> 16;  // RNE
  return (unsigned short)r;
}
__device__ __forceinline__ int cvtpk(float lo, float hi) {
  int r;
  asm("v_cvt_pk_bf16_f32 %0, %1, %2" : "=v"(r) : "v"(lo), "v"(hi));
  return r;
}
__device__ __forceinline__ void plswap(int &a, int &b) {
  asm("v_permlane32_swap_b32 %0, %1" : "+v"(a), "+v"(b));
}
__device__ __forceinline__ float fexp2(float x) {   // native v_exp_f32: 2^x, 1 inst
  float r;
  asm("v_exp_f32 %0, %1" : "=v"(r) : "v"(x));
  return r;
}
__device__ __forceinline__ void gload_lds16(const unsigned short* g, unsigned short* l) {
  __builtin_amdgcn_global_load_lds((const __attribute__((address_space(1))) void*)g,
                                   (__attribute__((address_space(3))) void*)l, 16, 0, 0);
}
__device__ __forceinline__ float fmax3(float a, float b, float c) {
  return fmaxf(fmaxf(a, b), c);   // fuses to v_max3_f32
}

// ---------------- f32 -> bf16 flat convert ----------------
__global__ __launch_bounds__(256) void k_convert(const float* __restrict__ in,
                                                 unsigned short* __restrict__ out, int n8) {
  int i = blockIdx.x * 256 + threadIdx.x;
  if (i < n8) {
    const float4 a = *(const float4*)(in + (size_t)i * 8);
    const float4 b = *(const float4*)(in + (size_t)i * 8 + 4);
    short8 v;
    v[0] = f2bf(a.x); v[1] = f2bf(a.y); v[2] = f2bf(a.z); v[3] = f2bf(a.w);
    v[4] = f2bf(b.x); v[5] = f2bf(b.y); v[6] = f2bf(b.z); v[7] = f2bf(b.w);
    *(short8*)(out + (size_t)i * 8) = v;
  }
}

// ---------------- transpose + f32->bf16 convert: out[c][r] = in[r][c] ----------------
__global__ __launch_bounds__(256) void k_transpose_cvt(const float* __restrict__ in,
                                                       unsigned short* __restrict__ out,
                                                       int R, int Cn) {
  __shared__ float tile[32][33];
  int tc = blockIdx.x * 32;
  int tr = blockIdx.y * 32;
  int lx = threadIdx.x & 31;
  int ly = threadIdx.x >> 5;  // 0..7
#pragma unroll
  for (int i = 0; i < 32; i += 8)
    tile[ly + i][lx] = in[(size_t)(tr + ly + i) * Cn + tc + lx];
  __syncthreads();
#pragma unroll
  for (int i = 0; i < 32; i += 8)
    out[(size_t)(tc + ly + i) * R + tr + lx] = f2bf(tile[lx][ly + i]);
}

// ---------------- QKV GEMM (m97 pattern): Xb bf16 @ Wt bf16 -> Q(scaled),K,Vt bf16 ----------------
__global__ __launch_bounds__(256) void k_qkv_gemm(const unsigned short* __restrict__ Xb,
                                                  const unsigned short* __restrict__ Wt,
                                                  const float* __restrict__ bias,
                                                  unsigned short* __restrict__ Qo,
                                                  unsigned short* __restrict__ Ko,
                                                  unsigned short* __restrict__ Vto) {
  __shared__ __align__(16) unsigned short As[128 * 32];
  __shared__ __align__(16) unsigned short Bs[128 * 32];
  int tid = threadIdx.x;
  int mb = blockIdx.x * 128;
  int nb = blockIdx.y * 128;
  int wid = tid >> 6, lane = tid & 63;
  int wr = (wid >> 1) * 64, wc = (wid & 1) * 64;
  int l15 = lane & 15, l4 = lane >> 4;
  int l16 = lane >> 2, lc = (lane & 3) * 8;   // staging row-within-16 / col
  f32x4 acc[4][4];
#pragma unroll
  for (int a = 0; a < 4; ++a)
#pragma unroll
    for (int b = 0; b < 4; ++b)
#pragma unroll
      for (int j = 0; j < 4; ++j) acc[a][b][j] = 0.0f;

  for (int kb = 0; kb < CCH; kb += 32) {
#pragma unroll
    for (int i = 0; i < 2; ++i) {
      int arow = wid * 32 + i * 16;
      gload_lds16(Xb + (size_t)(mb + arow + l16) * CCH + kb + lc, &As[arow * 32]);
      gload_lds16(Wt + (size_t)(nb + arow + l16) * CCH + kb + lc, &Bs[arow * 32]);
    }
    __syncthreads();
    short8 af[4], bfr[4];
#pragma unroll
    for (int mt = 0; mt < 4; ++mt) af[mt] = *(const short8*)(&As[(wr + mt * 16 + l15) * 32 + l4 * 8]);
#pragma unroll
    for (int nt = 0; nt < 4; ++nt) bfr[nt] = *(const short8*)(&Bs[(wc + nt * 16 + l15) * 32 + l4 * 8]);
#pragma unroll
    for (int mt = 0; mt < 4; ++mt)
#pragma unroll
      for (int nt = 0; nt < 4; ++nt)
        acc[mt][nt] = __builtin_amdgcn_mfma_f32_16x16x32_bf16(af[mt], bfr[nt], acc[mt][nt], 0, 0, 0);
    __syncthreads();
  }

#pragma unroll
  for (int mt = 0; mt < 4; ++mt) {
#pragma unroll
    for (int nt = 0; nt < 4; ++nt) {
      int gcol = nb + wc + nt * 16 + l15;        // 0..3071
      int which = gcol >> 10;
      int cc = gcol & 1023;
      int h = cc >> 6, d = cc & 63;
      float bv = bias[gcol];
#pragma unroll
      for (int j = 0; j < 4; ++j) {
        int grow = mb + wr + mt * 16 + l4 * 4 + j;  // 0..4095
        int b = grow >> 11, t = grow & 2047;
        float v = acc[mt][nt][j] + bv;
        size_t bh = (size_t)(b * HH + h);
        // fold sm_scale AND log2(e): softmax runs in exp2 domain
        if (which == 0)      Qo[(bh * TT + t) * DD + d] = f2bf(v * 0.18033688f);
        else if (which == 1) Ko[(bh * TT + t) * DD + d] = f2bf(v);
        else                 Vto[(bh * DD + d) * TT + t] = f2bf(v);
      }
    }
  }
}

// ---------------- causal flash attention: single-phase, counted-vmcnt pipeline ----------------
// 1024 blocks of 128 threads (2 waves x 32 q-rows = 64-row q-subtile), biggest jobs
// first. T4: prefetch loads stay in flight across raw s_barriers -- vmcnt never
// drains to 0 in the main loop. Writes normalized Yb directly.
__global__ __launch_bounds__(128) void k_attn(const unsigned short* __restrict__ Qb,
                                              const unsigned short* __restrict__ Kb,
                                              const unsigned short* __restrict__ Vtb,
                                              unsigned short* __restrict__ Y) {
  __shared__ __align__(16) unsigned short Ks[2][64 * 64];   // [kv][d], swizzled 16B chunks
  __shared__ __align__(16) unsigned short Vs[2][64 * 64];   // [d][kv], swizzled 16B chunks
  int tid = threadIdx.x;            // 0..127
  int jx = blockIdx.x;              // 0..1023
  int qsub = 31 - (jx >> 5);        // biggest jobs (32 tile-visits) dispatch first
  int bh = jx & 31;

  const unsigned short* Qp = Qb + (size_t)bh * TT * DD;
  const unsigned short* Kp = Kb + (size_t)bh * TT * DD;
  const unsigned short* Vp = Vtb + (size_t)bh * DD * TT;
  int wid = tid >> 6, lane = tid & 63;
  int l31 = lane & 31, h = lane >> 5;
  int q0 = qsub * 64 + wid * 32;
  int qrow = q0 + l31;

  short8 qf[4];
#pragma unroll
  for (int m = 0; m < 4; ++m)
    qf[m] = *(const short8*)(Qp + (size_t)qrow * DD + m * 16 + h * 8);

  f32x16 zv;
#pragma unroll
  for (int r = 0; r < 16; ++r) zv[r] = 0.0f;
  f32x16 po[2];
  po[0] = zv; po[1] = zv;
  float mrun = -1e30f, lrun = 0.0f;

  // prologue: stage tile 0 into buffer 0 (8 async loads; waited via vmcnt in iter 0)
#pragma unroll
  for (int i2 = 0; i2 < 4; ++i2) {
    int c = i2 * 128 + wid * 64 + lane;
    int srow = c >> 3, scol = ((c & 7) ^ (srow & 7)) * 8;
    int dst = (i2 * 128 + wid * 64) * 8;      // wave-uniform LDS base
    gload_lds16(Kp + (size_t)srow * DD + scol, &Ks[0][dst]);
    gload_lds16(Vp + (size_t)srow * TT + scol, &Vs[0][dst]);
  }

  int buf = 0;
  for (int t = 0; t <= qsub; ++t) {
    int kvb = t * 64;
    // (1) all waves finished reading buf^1 (previous compute) -> safe to overwrite
    __builtin_amdgcn_s_barrier();
    if (t < qsub) {                   // issue next tile into buf^1; keep 8 in flight
      int kvb2 = kvb + 64;
#pragma unroll
      for (int i2 = 0; i2 < 4; ++i2) {
        int c = i2 * 128 + wid * 64 + lane;
        int srow = c >> 3, scol = ((c & 7) ^ (srow & 7)) * 8;
        int dst = (i2 * 128 + wid * 64) * 8;
        gload_lds16(Kp + (size_t)(kvb2 + srow) * DD + scol, &Ks[buf ^ 1][dst]);
        gload_lds16(Vp + (size_t)srow * TT + kvb2 + scol, &Vs[buf ^ 1][dst]);
      }
      asm volatile("s_waitcnt vmcnt(8)" ::: "memory");   // tile-t loads done; t+1 in flight
    } else {
      asm volatile("s_waitcnt vmcnt(0)" ::: "memory");   // epilogue: drain
    }
    // (2) everyone's tile-t loads have landed in LDS
    __builtin_amdgcn_s_barrier();
    __builtin_amdgcn_sched_barrier(0);

    {
      f32x16 st[2];
      __builtin_amdgcn_s_setprio(1);
#pragma unroll
      for (int t32 = 0; t32 < 2; ++t32) {
        int row = t32 * 32 + l31;
        {
          int off = row * 64 + ((h ^ (row & 7)) * 8);
          short8 kf = *(const short8*)(&Ks[buf][off]);
          st[t32] = __builtin_amdgcn_mfma_f32_32x32x16_bf16(kf, qf[0], zv, 0, 0, 0);
        }
#pragma unroll
        for (int m = 1; m < 4; ++m) {
          int off = row * 64 + (((2 * m + h) ^ (row & 7)) * 8);
          short8 kf = *(const short8*)(&Ks[buf][off]);
          st[t32] = __builtin_amdgcn_mfma_f32_32x32x16_bf16(kf, qf[m], st[t32], 0, 0, 0);
        }
      }
      __builtin_amdgcn_s_setprio(0);

      if (kvb + 63 > q0) {            // diagonal tiles: causal mask
#pragma unroll
        for (int t32 = 0; t32 < 2; ++t32)
#pragma unroll
          for (int r = 0; r < 16; ++r) {
            int kvg = kvb + t32 * 32 + (r & 3) + 8 * (r >> 2) + 4 * h;
            if (kvg > qrow) st[t32][r] = -1e30f;
          }
      }

      // row max: v_max3 tree over 32 values, then cross-half
      float A = st[0][0], B = st[0][1], C = st[0][2], Dv = st[0][3];
#pragma unroll
      for (int r = 4; r < 16; r += 4) {
        A = fmax3(A, st[0][r], st[0][r + 1]);
        B = fmax3(B, st[0][r + 2], st[0][r + 3]);
        C = fmax3(C, st[1][r - 4], st[1][r - 3]);
        Dv = fmax3(Dv, st[1][r - 2], st[1][r - 1]);
      }
      C = fmax3(C, st[1][12], st[1][13]);
      Dv = fmax3(Dv, st[1][14], st[1][15]);
      float mx = fmaxf(fmax3(A, B, C), Dv);
      mx = fmaxf(mx, __shfl_xor(mx, 32));

      if (__any(mx - mrun > 8.0f)) {  // defer-max, log2 units
        float mnew = fmaxf(mrun, mx);
        float alpha = fexp2(mrun - mnew);
        lrun *= alpha;
#pragma unroll
        for (int dt = 0; dt < 2; ++dt)
#pragma unroll
          for (int r = 0; r < 16; ++r) po[dt][r] *= alpha;
        mrun = mnew;
      }

      float sum = 0.0f;
#pragma unroll
      for (int t32 = 0; t32 < 2; ++t32)
#pragma unroll
        for (int r = 0; r < 16; ++r) {
          float p = fexp2(st[t32][r] - mrun);
          st[t32][r] = p;
          sum += p;
        }
      sum += __shfl_xor(sum, 32);
      lrun += sum;

      // P -> bf16 B-fragments via cvt_pk + permlane32_swap
      short8 pf[4];
#pragma unroll
      for (int g = 0; g < 4; ++g) {
        int t32 = g >> 1, r0 = (g & 1) * 8;
        int a = cvtpk(st[t32][r0 + 0], st[t32][r0 + 1]);
        int b = cvtpk(st[t32][r0 + 4], st[t32][r0 + 5]);
        plswap(a, b);
        int c = cvtpk(st[t32][r0 + 2], st[t32][r0 + 3]);
        int d = cvtpk(st[t32][r0 + 6], st[t32][r0 + 7]);
        plswap(c, d);
        union { int w[4]; short8 s; } un;
        un.w[0] = a; un.w[1] = c; un.w[2] = b; un.w[3] = d;
        pf[g] = un.s;
      }

      // O^T += V^T . P
      __builtin_amdgcn_s_setprio(1);
#pragma unroll
      for (int dt = 0; dt < 2; ++dt) {
#pragma unroll
        for (int g = 0; g < 4; ++g) {
          int row = dt * 32 + l31;
          int off = row * 64 + (((2 * g + h) ^ (row & 7)) * 8);
          short8 vf = *(const short8*)(&Vs[buf][off]);
          po[dt] = __builtin_amdgcn_mfma_f32_32x32x16_bf16(vf, pf[g], po[dt], 0, 0, 0);
        }
      }
      __builtin_amdgcn_s_setprio(0);
    }

    buf ^= 1;
  }

  // normalize + write Yb directly
  float inv = 1.0f / lrun;
  int b = bh >> 4, hh = bh & 15;
  int trow = qsub * 64 + wid * 32 + l31;
  unsigned short* yp = Y + ((size_t)(b * TT + trow)) * CCH + hh * DD;
#pragma unroll
  for (int dt = 0; dt < 2; ++dt)
#pragma unroll
    for (int r = 0; r < 16; r += 2) {
      int d = dt * 32 + (r & 3) + 8 * (r >> 2) + 4 * h;
      *(int*)(yp + d) = cvtpk(po[dt][r] * inv, po[dt][r + 1] * inv);
    }
}

// ---------------- proj GEMM (m97 pattern): Yb bf16 @ Wt_proj bf16 + bias -> f32 out ----------------
__global__ __launch_bounds__(256) void k_proj_gemm(const unsigned short* __restrict__ Yb,
                                                   const unsigned short* __restrict__ Wt,
                                                   const float* __restrict__ bias,
                                                   float* __restrict__ Out) {
  __shared__ __align__(16) unsigned short As[128 * 32];
  __shared__ __align__(16) unsigned short Bs[128 * 32];
  int tid = threadIdx.x;
  int mb = blockIdx.x * 128;
  int nb = blockIdx.y * 128;
  int wid = tid >> 6, lane = tid & 63;
  int wr = (wid >> 1) * 64, wc = (wid & 1) * 64;
  int l15 = lane & 15, l4 = lane >> 4;
  int l16 = lane >> 2, lc = (lane & 3) * 8;
  f32x4 acc[4][4];
#pragma unroll
  for (int a = 0; a < 4; ++a)
#pragma unroll
    for (int b = 0; b < 4; ++b)
#pragma unroll
      for (int j = 0; j < 4; ++j) acc[a][b][j] = 0.0f;

  for (int kb = 0; kb < CCH; kb += 32) {
#pragma unroll
    for (int i = 0; i < 2; ++i) {
      int arow = wid * 32 + i * 16;
      gload_lds16(Yb + (size_t)(mb + arow + l16) * CCH + kb + lc, &As[arow * 32]);
      gload_lds16(Wt + (size_t)(nb + arow + l16) * CCH + kb + lc, &Bs[arow * 32]);
    }
    __syncthreads();
    short8 af[4], bfr[4];
#pragma unroll
    for (int mt = 0; mt < 4; ++mt) af[mt] = *(const short8*)(&As[(wr + mt * 16 + l15) * 32 + l4 * 8]);
#pragma unroll
    for (int nt = 0; nt < 4; ++nt) bfr[nt] = *(const short8*)(&Bs[(wc + nt * 16 + l15) * 32 + l4 * 8]);
#pragma unroll
    for (int mt = 0; mt < 4; ++mt)
#pragma unroll
      for (int nt = 0; nt < 4; ++nt)
        acc[mt][nt] = __builtin_amdgcn_mfma_f32_16x16x32_bf16(af[mt], bfr[nt], acc[mt][nt], 0, 0, 0);
    __syncthreads();
  }

#pragma unroll
  for (int mt = 0; mt < 4; ++mt) {
#pragma unroll
    for (int nt = 0; nt < 4; ++nt) {
      int gcol = nb + wc + nt * 16 + l15;
      float bv = bias[gcol];
#pragma unroll
      for (int j = 0; j < 4; ++j) {
        int grow = mb + wr + mt * 16 + l4 * 4 + j;
        Out[(size_t)grow * CCH + gcol] = acc[mt][nt][j] + bv;
      }
    }
  }
}

extern "C" void kernel_launch(void* const* d_in, const int* in_sizes, int n_in,
                              void* d_out, int out_size, void* d_ws, size_t ws_size,
                              hipStream_t stream) {
  const float* x      = (const float*)d_in[0];
  const float* W_qkv  = (const float*)d_in[1];
  const float* b_qkv  = (const float*)d_in[2];
  const float* W_proj = (const float*)d_in[3];
  const float* b_proj = (const float*)d_in[4];
  float* out = (float*)d_out;

  char* ws = (char*)d_ws;
  size_t off = 0;
  unsigned short* Wt_qkv  = (unsigned short*)(ws + off); off += (size_t)N3 * CCH * 2;   // 6.3 MB
  unsigned short* Wt_proj = (unsigned short*)(ws + off); off += (size_t)CCH * CCH * 2;  // 2.1 MB
  unsigned short* Xb      = (unsigned short*)(ws + off); off += (size_t)BT * CCH * 2;   // 8.4 MB
  unsigned short* Qb      = (unsigned short*)(ws + off); off += (size_t)BT * CCH * 2;   // 8.4 MB
  unsigned short* Kb      = (unsigned short*)(ws + off); off += (size_t)BT * CCH * 2;   // 8.4 MB
  unsigned short* Vt      = (unsigned short*)(ws + off); off += (size_t)BT * CCH * 2;   // 8.4 MB
  unsigned short* Yb      = (unsigned short*)(ws + off); off += (size_t)BT * CCH * 2;   // 8.4 MB

  k_convert<<<dim3(BT * CCH / 8 / 256), 256, 0, stream>>>(x, Xb, BT * CCH / 8);
  k_transpose_cvt<<<dim3(N3 / 32, CCH / 32), 256, 0, stream>>>(W_qkv, Wt_qkv, CCH, N3);
  k_transpose_cvt<<<dim3(CCH / 32, CCH / 32), 256, 0, stream>>>(W_proj, Wt_proj, CCH, CCH);
  k_qkv_gemm<<<dim3(BT / 128, N3 / 128), 256, 0, stream>>>(Xb, Wt_qkv, b_qkv, Qb, Kb, Vt);
  k_attn<<<dim3(1024), 128, 0, stream>>>(Qb, Kb, Vt, Yb);
  k_proj_gemm<<<dim3(BT / 128, CCH / 128), 256, 0, stream>>>(Yb, Wt_proj, b_proj, out);
}

// Round 12
// 120.413 us; speedup vs baseline: 1.0491x; 1.0491x over previous
//
#include <hip/hip_runtime.h>
#include <hip/hip_bf16.h>
#include <math.h>

#define BB 2
#define TT 2048
#define CCH 1024
#define HH 16
#define DD 64
#define BT (BB*TT)     // 4096
#define N3 (3*CCH)     // 3072

typedef __attribute__((ext_vector_type(8))) short short8;
typedef __attribute__((ext_vector_type(4))) float f32x4;
typedef __attribute__((ext_vector_type(16))) float f32x16;

__device__ __forceinline__ unsigned short f2bf(float f) {
  unsigned int u = __float_as_uint(f);
  unsigned int r = (u + 0x7FFFu + ((u >> 16) & 1u)) >> 16;  // RNE
  return (unsigned short)r;
}
__device__ __forceinline__ int cvtpk(float lo, float hi) {
  int r;
  asm("v_cvt_pk_bf16_f32 %0, %1, %2" : "=v"(r) : "v"(lo), "v"(hi));
  return r;
}
__device__ __forceinline__ void plswap(int &a, int &b) {
  asm("v_permlane32_swap_b32 %0, %1" : "+v"(a), "+v"(b));
}
__device__ __forceinline__ float fexp2(float x) {   // native v_exp_f32: 2^x, 1 inst
  float r;
  asm("v_exp_f32 %0, %1" : "=v"(r) : "v"(x));
  return r;
}
__device__ __forceinline__ void gload_lds16(const unsigned short* g, unsigned short* l) {
  __builtin_amdgcn_global_load_lds((const __attribute__((address_space(1))) void*)g,
                                   (__attribute__((address_space(3))) void*)l, 16, 0, 0);
}
__device__ __forceinline__ float fmax3(float a, float b, float c) {
  return fmaxf(fmaxf(a, b), c);   // fuses to v_max3_f32
}

// ---------------- f32 -> bf16 flat convert ----------------
__global__ __launch_bounds__(256) void k_convert(const float* __restrict__ in,
                                                 unsigned short* __restrict__ out, int n8) {
  int i = blockIdx.x * 256 + threadIdx.x;
  if (i < n8) {
    const float4 a = *(const float4*)(in + (size_t)i * 8);
    const float4 b = *(const float4*)(in + (size_t)i * 8 + 4);
    short8 v;
    v[0] = f2bf(a.x); v[1] = f2bf(a.y); v[2] = f2bf(a.z); v[3] = f2bf(a.w);
    v[4] = f2bf(b.x); v[5] = f2bf(b.y); v[6] = f2bf(b.z); v[7] = f2bf(b.w);
    *(short8*)(out + (size_t)i * 8) = v;
  }
}

// ---------------- transpose + f32->bf16 convert: out[c][r] = in[r][c] ----------------
__global__ __launch_bounds__(256) void k_transpose_cvt(const float* __restrict__ in,
                                                       unsigned short* __restrict__ out,
                                                       int R, int Cn) {
  __shared__ float tile[32][33];
  int tc = blockIdx.x * 32;
  int tr = blockIdx.y * 32;
  int lx = threadIdx.x & 31;
  int ly = threadIdx.x >> 5;  // 0..7
#pragma unroll
  for (int i = 0; i < 32; i += 8)
    tile[ly + i][lx] = in[(size_t)(tr + ly + i) * Cn + tc + lx];
  __syncthreads();
#pragma unroll
  for (int i = 0; i < 32; i += 8)
    out[(size_t)(tc + ly + i) * R + tr + lx] = f2bf(tile[lx][ly + i]);
}

// ---------------- QKV GEMM (m97 pattern): Xb bf16 @ Wt bf16 -> Q(scaled),K,Vt bf16 ----------------
__global__ __launch_bounds__(256) void k_qkv_gemm(const unsigned short* __restrict__ Xb,
                                                  const unsigned short* __restrict__ Wt,
                                                  const float* __restrict__ bias,
                                                  unsigned short* __restrict__ Qo,
                                                  unsigned short* __restrict__ Ko,
                                                  unsigned short* __restrict__ Vto) {
  __shared__ __align__(16) unsigned short As[128 * 32];
  __shared__ __align__(16) unsigned short Bs[128 * 32];
  int tid = threadIdx.x;
  int mb = blockIdx.x * 128;
  int nb = blockIdx.y * 128;
  int wid = tid >> 6, lane = tid & 63;
  int wr = (wid >> 1) * 64, wc = (wid & 1) * 64;
  int l15 = lane & 15, l4 = lane >> 4;
  int l16 = lane >> 2, lc = (lane & 3) * 8;   // staging row-within-16 / col
  f32x4 acc[4][4];
#pragma unroll
  for (int a = 0; a < 4; ++a)
#pragma unroll
    for (int b = 0; b < 4; ++b)
#pragma unroll
      for (int j = 0; j < 4; ++j) acc[a][b][j] = 0.0f;

  for (int kb = 0; kb < CCH; kb += 32) {
#pragma unroll
    for (int i = 0; i < 2; ++i) {
      int arow = wid * 32 + i * 16;
      gload_lds16(Xb + (size_t)(mb + arow + l16) * CCH + kb + lc, &As[arow * 32]);
      gload_lds16(Wt + (size_t)(nb + arow + l16) * CCH + kb + lc, &Bs[arow * 32]);
    }
    __syncthreads();
    short8 af[4], bfr[4];
#pragma unroll
    for (int mt = 0; mt < 4; ++mt) af[mt] = *(const short8*)(&As[(wr + mt * 16 + l15) * 32 + l4 * 8]);
#pragma unroll
    for (int nt = 0; nt < 4; ++nt) bfr[nt] = *(const short8*)(&Bs[(wc + nt * 16 + l15) * 32 + l4 * 8]);
#pragma unroll
    for (int mt = 0; mt < 4; ++mt)
#pragma unroll
      for (int nt = 0; nt < 4; ++nt)
        acc[mt][nt] = __builtin_amdgcn_mfma_f32_16x16x32_bf16(af[mt], bfr[nt], acc[mt][nt], 0, 0, 0);
    __syncthreads();
  }

#pragma unroll
  for (int mt = 0; mt < 4; ++mt) {
#pragma unroll
    for (int nt = 0; nt < 4; ++nt) {
      int gcol = nb + wc + nt * 16 + l15;        // 0..3071
      int which = gcol >> 10;
      int cc = gcol & 1023;
      int h = cc >> 6, d = cc & 63;
      float bv = bias[gcol];
#pragma unroll
      for (int j = 0; j < 4; ++j) {
        int grow = mb + wr + mt * 16 + l4 * 4 + j;  // 0..4095
        int b = grow >> 11, t = grow & 2047;
        float v = acc[mt][nt][j] + bv;
        size_t bh = (size_t)(b * HH + h);
        // fold sm_scale AND log2(e): softmax runs in exp2 domain
        if (which == 0)      Qo[(bh * TT + t) * DD + d] = f2bf(v * 0.18033688f);
        else if (which == 1) Ko[(bh * TT + t) * DD + d] = f2bf(v);
        else                 Vto[(bh * DD + d) * TT + t] = f2bf(v);
      }
    }
  }
}

// ---------------- causal flash attention: 2 independent waves per 32-row q-tile ----------------
// Block = 32 q-rows; wave 0 processes even 64-wide KV tiles, wave 1 odd, each with a
// PRIVATE single-buffered LDS tile (no __syncthreads in the main loop; per-wave vmcnt).
// Prefetch of own next tile issues after frags are in regs (lgkmcnt(0)) and flies under
// softmax+PV. Ends with a tiny online-softmax merge of the two partials via LDS.
__global__ __launch_bounds__(128) void k_attn(const unsigned short* __restrict__ Qb,
                                              const unsigned short* __restrict__ Kb,
                                              const unsigned short* __restrict__ Vtb,
                                              unsigned short* __restrict__ Y) {
  __shared__ __align__(16) unsigned short Ks[2][64 * 64];   // per-wave [kv][d], swizzled chunks
  __shared__ __align__(16) unsigned short Vs[2][64 * 64];   // per-wave [d][kv], swizzled chunks
  int tid = threadIdx.x;            // 0..127
  int jx = blockIdx.x;              // 0..2047
  int j = 63 - (jx >> 5);           // 32-row q-subtile, biggest jobs first
  int bh = jx & 31;
  int wid = tid >> 6, lane = tid & 63;
  int l31 = lane & 31, h = lane >> 5;
  int q0 = j * 32;
  int qrow = q0 + l31;
  int tmax = j >> 1;                // last 64-wide KV tile index

  const unsigned short* Qp = Qb + (size_t)bh * TT * DD;
  const unsigned short* Kp = Kb + (size_t)bh * TT * DD;
  const unsigned short* Vp = Vtb + (size_t)bh * DD * TT;

  short8 qf[4];
#pragma unroll
  for (int m = 0; m < 4; ++m)
    qf[m] = *(const short8*)(Qp + (size_t)qrow * DD + m * 16 + h * 8);

  f32x16 zv;
#pragma unroll
  for (int r = 0; r < 16; ++r) zv[r] = 0.0f;
  f32x16 po[2];
  po[0] = zv; po[1] = zv;
  float mrun = -1e30f, lrun = 0.0f;

  // prologue: stage own first tile (t = wid) into private buffer
  if (wid <= tmax) {
#pragma unroll
    for (int i = 0; i < 8; ++i) {
      int c = i * 64 + lane;
      int srow = c >> 3, scol = ((c & 7) ^ (srow & 7)) * 8;
      gload_lds16(Kp + (size_t)(wid * 64 + srow) * DD + scol, &Ks[wid][i * 512]);
      gload_lds16(Vp + (size_t)srow * TT + wid * 64 + scol, &Vs[wid][i * 512]);
    }
  }

  for (int t = wid; t <= tmax; t += 2) {
    int kvb = t * 64;
    asm volatile("s_waitcnt vmcnt(0)" ::: "memory");   // own tile landed (per-wave counter)
    __builtin_amdgcn_sched_barrier(0);

    // K-fragments -> regs, QK^T
    short8 kf[2][4];
#pragma unroll
    for (int t32 = 0; t32 < 2; ++t32) {
      int row = t32 * 32 + l31;
#pragma unroll
      for (int m = 0; m < 4; ++m)
        kf[t32][m] = *(const short8*)(&Ks[wid][row * 64 + (((2 * m + h) ^ (row & 7)) * 8)]);
    }
    f32x16 st[2];
    __builtin_amdgcn_s_setprio(1);
#pragma unroll
    for (int t32 = 0; t32 < 2; ++t32) {
      st[t32] = __builtin_amdgcn_mfma_f32_32x32x16_bf16(kf[t32][0], qf[0], zv, 0, 0, 0);
#pragma unroll
      for (int m = 1; m < 4; ++m)
        st[t32] = __builtin_amdgcn_mfma_f32_32x32x16_bf16(kf[t32][m], qf[m], st[t32], 0, 0, 0);
    }
    __builtin_amdgcn_s_setprio(0);

    // V-fragments -> regs (must precede overwrite of own buffer)
    short8 vf[2][4];
#pragma unroll
    for (int dt = 0; dt < 2; ++dt) {
      int row = dt * 32 + l31;
#pragma unroll
      for (int g = 0; g < 4; ++g)
        vf[dt][g] = *(const short8*)(&Vs[wid][row * 64 + (((2 * g + h) ^ (row & 7)) * 8)]);
    }
    asm volatile("s_waitcnt lgkmcnt(0)" ::: "memory");  // all ds_reads done -> safe to restage
    __builtin_amdgcn_sched_barrier(0);

    if (t + 2 <= tmax) {              // issue own next tile; flies under softmax+PV
      int kvb2 = kvb + 128;
#pragma unroll
      for (int i = 0; i < 8; ++i) {
        int c = i * 64 + lane;
        int srow = c >> 3, scol = ((c & 7) ^ (srow & 7)) * 8;
        gload_lds16(Kp + (size_t)(kvb2 + srow) * DD + scol, &Ks[wid][i * 512]);
        gload_lds16(Vp + (size_t)srow * TT + kvb2 + scol, &Vs[wid][i * 512]);
      }
    }

    if (kvb + 63 > q0) {              // diagonal tiles: causal mask
#pragma unroll
      for (int t32 = 0; t32 < 2; ++t32)
#pragma unroll
        for (int r = 0; r < 16; ++r) {
          int kvg = kvb + t32 * 32 + (r & 3) + 8 * (r >> 2) + 4 * h;
          if (kvg > qrow) st[t32][r] = -1e30f;
        }
    }

    // row max: v_max3 tree over 32 values, then cross-half
    float A = st[0][0], B = st[0][1], C = st[0][2], Dv = st[0][3];
#pragma unroll
    for (int r = 4; r < 16; r += 4) {
      A = fmax3(A, st[0][r], st[0][r + 1]);
      B = fmax3(B, st[0][r + 2], st[0][r + 3]);
      C = fmax3(C, st[1][r - 4], st[1][r - 3]);
      Dv = fmax3(Dv, st[1][r - 2], st[1][r - 1]);
    }
    C = fmax3(C, st[1][12], st[1][13]);
    Dv = fmax3(Dv, st[1][14], st[1][15]);
    float mx = fmaxf(fmax3(A, B, C), Dv);
    mx = fmaxf(mx, __shfl_xor(mx, 32));

    if (__any(mx - mrun > 8.0f)) {    // defer-max, log2 units
      float mnew = fmaxf(mrun, mx);
      float alpha = fexp2(mrun - mnew);
      lrun *= alpha;
#pragma unroll
      for (int dt = 0; dt < 2; ++dt)
#pragma unroll
        for (int r = 0; r < 16; ++r) po[dt][r] *= alpha;
      mrun = mnew;
    }

    float sum = 0.0f;
#pragma unroll
    for (int t32 = 0; t32 < 2; ++t32)
#pragma unroll
      for (int r = 0; r < 16; ++r) {
        float p = fexp2(st[t32][r] - mrun);
        st[t32][r] = p;
        sum += p;
      }
    sum += __shfl_xor(sum, 32);
    lrun += sum;

    // P -> bf16 B-fragments via cvt_pk + permlane32_swap
    short8 pf[4];
#pragma unroll
    for (int g = 0; g < 4; ++g) {
      int t32 = g >> 1, r0 = (g & 1) * 8;
      int a = cvtpk(st[t32][r0 + 0], st[t32][r0 + 1]);
      int b = cvtpk(st[t32][r0 + 4], st[t32][r0 + 5]);
      plswap(a, b);
      int c = cvtpk(st[t32][r0 + 2], st[t32][r0 + 3]);
      int d = cvtpk(st[t32][r0 + 6], st[t32][r0 + 7]);
      plswap(c, d);
      union { int w[4]; short8 s; } un;
      un.w[0] = a; un.w[1] = c; un.w[2] = b; un.w[3] = d;
      pf[g] = un.s;
    }

    // O^T += V^T . P  (from regs)
    __builtin_amdgcn_s_setprio(1);
#pragma unroll
    for (int dt = 0; dt < 2; ++dt)
#pragma unroll
      for (int g = 0; g < 4; ++g)
        po[dt] = __builtin_amdgcn_mfma_f32_32x32x16_bf16(vf[dt][g], pf[g], po[dt], 0, 0, 0);
    __builtin_amdgcn_s_setprio(0);
  }

  // drain any stray in-flight loads before LDS reuse, then merge the two partials
  asm volatile("s_waitcnt vmcnt(0)" ::: "memory");
  __syncthreads();
  float* ex   = (float*)&Ks[0][0];    // 64 lanes x 33-pad floats = 8448 B (spans Ks)
  float* exml = (float*)&Vs[0][0];
  if (wid == 1) {
#pragma unroll
    for (int dt = 0; dt < 2; ++dt)
#pragma unroll
      for (int r = 0; r < 16; ++r) ex[lane * 33 + dt * 16 + r] = po[dt][r];
    exml[lane] = mrun;
    exml[64 + lane] = lrun;
  }
  __syncthreads();
  if (wid == 0) {
    float m1 = exml[lane], l1 = exml[64 + lane];
    float M = fmaxf(mrun, m1);
    float a0 = fexp2(mrun - M), a1 = fexp2(m1 - M);
    float inv = 1.0f / (lrun * a0 + l1 * a1);
    a0 *= inv; a1 *= inv;
    int b = bh >> 4, hh = bh & 15;
    unsigned short* yp = Y + ((size_t)(b * TT + qrow)) * CCH + hh * DD;
#pragma unroll
    for (int dt = 0; dt < 2; ++dt)
#pragma unroll
      for (int r = 0; r < 16; r += 2) {
        int d = dt * 32 + (r & 3) + 8 * (r >> 2) + 4 * h;
        float v0 = po[dt][r]     * a0 + ex[lane * 33 + dt * 16 + r]     * a1;
        float v1 = po[dt][r + 1] * a0 + ex[lane * 33 + dt * 16 + r + 1] * a1;
        *(int*)(yp + d) = cvtpk(v0, v1);
      }
  }
}

// ---------------- proj GEMM (m97 pattern): Yb bf16 @ Wt_proj bf16 + bias -> f32 out ----------------
__global__ __launch_bounds__(256) void k_proj_gemm(const unsigned short* __restrict__ Yb,
                                                   const unsigned short* __restrict__ Wt,
                                                   const float* __restrict__ bias,
                                                   float* __restrict__ Out) {
  __shared__ __align__(16) unsigned short As[128 * 32];
  __shared__ __align__(16) unsigned short Bs[128 * 32];
  int tid = threadIdx.x;
  int mb = blockIdx.x * 128;
  int nb = blockIdx.y * 128;
  int wid = tid >> 6, lane = tid & 63;
  int wr = (wid >> 1) * 64, wc = (wid & 1) * 64;
  int l15 = lane & 15, l4 = lane >> 4;
  int l16 = lane >> 2, lc = (lane & 3) * 8;
  f32x4 acc[4][4];
#pragma unroll
  for (int a = 0; a < 4; ++a)
#pragma unroll
    for (int b = 0; b < 4; ++b)
#pragma unroll
      for (int j = 0; j < 4; ++j) acc[a][b][j] = 0.0f;

  for (int kb = 0; kb < CCH; kb += 32) {
#pragma unroll
    for (int i = 0; i < 2; ++i) {
      int arow = wid * 32 + i * 16;
      gload_lds16(Yb + (size_t)(mb + arow + l16) * CCH + kb + lc, &As[arow * 32]);
      gload_lds16(Wt + (size_t)(nb + arow + l16) * CCH + kb + lc, &Bs[arow * 32]);
    }
    __syncthreads();
    short8 af[4], bfr[4];
#pragma unroll
    for (int mt = 0; mt < 4; ++mt) af[mt] = *(const short8*)(&As[(wr + mt * 16 + l15) * 32 + l4 * 8]);
#pragma unroll
    for (int nt = 0; nt < 4; ++nt) bfr[nt] = *(const short8*)(&Bs[(wc + nt * 16 + l15) * 32 + l4 * 8]);
#pragma unroll
    for (int mt = 0; mt < 4; ++mt)
#pragma unroll
      for (int nt = 0; nt < 4; ++nt)
        acc[mt][nt] = __builtin_amdgcn_mfma_f32_16x16x32_bf16(af[mt], bfr[nt], acc[mt][nt], 0, 0, 0);
    __syncthreads();
  }

#pragma unroll
  for (int mt = 0; mt < 4; ++mt) {
#pragma unroll
    for (int nt = 0; nt < 4; ++nt) {
      int gcol = nb + wc + nt * 16 + l15;
      float bv = bias[gcol];
#pragma unroll
      for (int j = 0; j < 4; ++j) {
        int grow = mb + wr + mt * 16 + l4 * 4 + j;
        Out[(size_t)grow * CCH + gcol] = acc[mt][nt][j] + bv;
      }
    }
  }
}

extern "C" void kernel_launch(void* const* d_in, const int* in_sizes, int n_in,
                              void* d_out, int out_size, void* d_ws, size_t ws_size,
                              hipStream_t stream) {
  const float* x      = (const float*)d_in[0];
  const float* W_qkv  = (const float*)d_in[1];
  const float* b_qkv  = (const float*)d_in[2];
  const float* W_proj = (const float*)d_in[3];
  const float* b_proj = (const float*)d_in[4];
  float* out = (float*)d_out;

  char* ws = (char*)d_ws;
  size_t off = 0;
  unsigned short* Wt_qkv  = (unsigned short*)(ws + off); off += (size_t)N3 * CCH * 2;   // 6.3 MB
  unsigned short* Wt_proj = (unsigned short*)(ws + off); off += (size_t)CCH * CCH * 2;  // 2.1 MB
  unsigned short* Xb      = (unsigned short*)(ws + off); off += (size_t)BT * CCH * 2;   // 8.4 MB
  unsigned short* Qb      = (unsigned short*)(ws + off); off += (size_t)BT * CCH * 2;   // 8.4 MB
  unsigned short* Kb      = (unsigned short*)(ws + off); off += (size_t)BT * CCH * 2;   // 8.4 MB
  unsigned short* Vt      = (unsigned short*)(ws + off); off += (size_t)BT * CCH * 2;   // 8.4 MB
  unsigned short* Yb      = (unsigned short*)(ws + off); off += (size_t)BT * CCH * 2;   // 8.4 MB

  k_convert<<<dim3(BT * CCH / 8 / 256), 256, 0, stream>>>(x, Xb, BT * CCH / 8);
  k_transpose_cvt<<<dim3(N3 / 32, CCH / 32), 256, 0, stream>>>(W_qkv, Wt_qkv, CCH, N3);
  k_transpose_cvt<<<dim3(CCH / 32, CCH / 32), 256, 0, stream>>>(W_proj, Wt_proj, CCH, CCH);
  k_qkv_gemm<<<dim3(BT / 128, N3 / 128), 256, 0, stream>>>(Xb, Wt_qkv, b_qkv, Qb, Kb, Vt);
  k_attn<<<dim3(2048), 128, 0, stream>>>(Qb, Kb, Vt, Yb);
  k_proj_gemm<<<dim3(BT / 128, CCH / 128), 256, 0, stream>>>(Yb, Wt_proj, b_proj, out);
}

// Round 13
// 109.428 us; speedup vs baseline: 1.1544x; 1.1004x over previous
//
#include <hip/hip_runtime.h>
#include <hip/hip_bf16.h>
#include <math.h>

#define BB 2
#define TT 2048
#define CCH 1024
#define HH 16
#define DD 64
#define BT (BB*TT)     // 4096
#define N3 (3*CCH)     // 3072

typedef __attribute__((ext_vector_type(8))) short short8;
typedef __attribute__((ext_vector_type(4))) float f32x4;
typedef __attribute__((ext_vector_type(16))) float f32x16;

__device__ __forceinline__ unsigned short f2bf(float f) {
  unsigned int u = __float_as_uint(f);
  unsigned int r = (u + 0x7FFFu + ((u >> 16) & 1u)) >> 16;  // RNE
  return (unsigned short)r;
}
__device__ __forceinline__ int cvtpk(float lo, float hi) {
  int r;
  asm("v_cvt_pk_bf16_f32 %0, %1, %2" : "=v"(r) : "v"(lo), "v"(hi));
  return r;
}
__device__ __forceinline__ void plswap(int &a, int &b) {
  asm("v_permlane32_swap_b32 %0, %1" : "+v"(a), "+v"(b));
}
__device__ __forceinline__ float fexp2(float x) {   // native v_exp_f32: 2^x, 1 inst
  float r;
  asm("v_exp_f32 %0, %1" : "=v"(r) : "v"(x));
  return r;
}
__device__ __forceinline__ void gload_lds16(const unsigned short* g, unsigned short* l) {
  __builtin_amdgcn_global_load_lds((const __attribute__((address_space(1))) void*)g,
                                   (__attribute__((address_space(3))) void*)l, 16, 0, 0);
}
__device__ __forceinline__ float fmax3(float a, float b, float c) {
  return fmaxf(fmaxf(a, b), c);   // fuses to v_max3_f32
}

// Fragment-ordered layouts (per-bh buffers of TT*DD bf16):
//  row-frag (Q and K):  addr(r, d) = ((r>>5)*4 + (d>>4))*512 + ((d>>3)&1)*256 + (r&31)*8 + (d&7)
//    -> wave read for (32-row group G=r>>5, m): base (G*4+m)*512 + lane*8, lane = h*32+l31
//  col-frag (V):        addr(t, d) = (((t>>6)*2 + (d>>5))*4 + ((t>>4)&3))*512
//                                    + (((t>>3)&1)*32 + (d&31))*8 + (t&7)
//    -> wave read for (tile, dt, g): base ((tile*2+dt)*4+g)*512 + lane*8

// ---------------- f32 -> bf16 flat convert ----------------
__global__ __launch_bounds__(256) void k_convert(const float* __restrict__ in,
                                                 unsigned short* __restrict__ out, int n8) {
  int i = blockIdx.x * 256 + threadIdx.x;
  if (i < n8) {
    const float4 a = *(const float4*)(in + (size_t)i * 8);
    const float4 b = *(const float4*)(in + (size_t)i * 8 + 4);
    short8 v;
    v[0] = f2bf(a.x); v[1] = f2bf(a.y); v[2] = f2bf(a.z); v[3] = f2bf(a.w);
    v[4] = f2bf(b.x); v[5] = f2bf(b.y); v[6] = f2bf(b.z); v[7] = f2bf(b.w);
    *(short8*)(out + (size_t)i * 8) = v;
  }
}

// ---------------- transpose + f32->bf16 convert: out[c][r] = in[r][c] ----------------
__global__ __launch_bounds__(256) void k_transpose_cvt(const float* __restrict__ in,
                                                       unsigned short* __restrict__ out,
                                                       int R, int Cn) {
  __shared__ float tile[32][33];
  int tc = blockIdx.x * 32;
  int tr = blockIdx.y * 32;
  int lx = threadIdx.x & 31;
  int ly = threadIdx.x >> 5;  // 0..7
#pragma unroll
  for (int i = 0; i < 32; i += 8)
    tile[ly + i][lx] = in[(size_t)(tr + ly + i) * Cn + tc + lx];
  __syncthreads();
#pragma unroll
  for (int i = 0; i < 32; i += 8)
    out[(size_t)(tc + ly + i) * R + tr + lx] = f2bf(tile[lx][ly + i]);
}

// ---------------- QKV GEMM (m97 pattern) -> fragment-ordered Qf(scaled), Kf, Vf ----------------
__global__ __launch_bounds__(256) void k_qkv_gemm(const unsigned short* __restrict__ Xb,
                                                  const unsigned short* __restrict__ Wt,
                                                  const float* __restrict__ bias,
                                                  unsigned short* __restrict__ Qf,
                                                  unsigned short* __restrict__ Kf,
                                                  unsigned short* __restrict__ Vf) {
  __shared__ __align__(16) unsigned short As[128 * 32];
  __shared__ __align__(16) unsigned short Bs[128 * 32];
  int tid = threadIdx.x;
  int mb = blockIdx.x * 128;
  int nb = blockIdx.y * 128;
  int wid = tid >> 6, lane = tid & 63;
  int wr = (wid >> 1) * 64, wc = (wid & 1) * 64;
  int l15 = lane & 15, l4 = lane >> 4;
  int l16 = lane >> 2, lc = (lane & 3) * 8;   // staging row-within-16 / col
  f32x4 acc[4][4];
#pragma unroll
  for (int a = 0; a < 4; ++a)
#pragma unroll
    for (int b = 0; b < 4; ++b)
#pragma unroll
      for (int j = 0; j < 4; ++j) acc[a][b][j] = 0.0f;

  for (int kb = 0; kb < CCH; kb += 32) {
#pragma unroll
    for (int i = 0; i < 2; ++i) {
      int arow = wid * 32 + i * 16;
      gload_lds16(Xb + (size_t)(mb + arow + l16) * CCH + kb + lc, &As[arow * 32]);
      gload_lds16(Wt + (size_t)(nb + arow + l16) * CCH + kb + lc, &Bs[arow * 32]);
    }
    __syncthreads();
    short8 af[4], bfr[4];
#pragma unroll
    for (int mt = 0; mt < 4; ++mt) af[mt] = *(const short8*)(&As[(wr + mt * 16 + l15) * 32 + l4 * 8]);
#pragma unroll
    for (int nt = 0; nt < 4; ++nt) bfr[nt] = *(const short8*)(&Bs[(wc + nt * 16 + l15) * 32 + l4 * 8]);
#pragma unroll
    for (int mt = 0; mt < 4; ++mt)
#pragma unroll
      for (int nt = 0; nt < 4; ++nt)
        acc[mt][nt] = __builtin_amdgcn_mfma_f32_16x16x32_bf16(af[mt], bfr[nt], acc[mt][nt], 0, 0, 0);
    __syncthreads();
  }

#pragma unroll
  for (int mt = 0; mt < 4; ++mt) {
#pragma unroll
    for (int nt = 0; nt < 4; ++nt) {
      int gcol = nb + wc + nt * 16 + l15;        // 0..3071
      int which = gcol >> 10;
      int cc = gcol & 1023;
      int hh = cc >> 6, d = cc & 63;
      float bv = bias[gcol];
#pragma unroll
      for (int j = 0; j < 4; ++j) {
        int grow = mb + wr + mt * 16 + l4 * 4 + j;  // 0..4095
        int b = grow >> 11, t = grow & 2047;
        float v = acc[mt][nt][j] + bv;
        size_t bh = (size_t)(b * HH + hh) * TT * DD;
        if (which == 2) {
          // col-frag (V)
          size_t a = (size_t)((((t >> 6) * 2 + (d >> 5)) * 4 + ((t >> 4) & 3)) * 512
                             + (((t >> 3) & 1) * 32 + (d & 31)) * 8 + (t & 7));
          Vf[bh + a] = f2bf(v);
        } else {
          // row-frag (Q scaled by sm_scale*log2e for exp2-domain softmax, K plain)
          size_t a = (size_t)(((t >> 5) * 4 + (d >> 4)) * 512
                             + ((d >> 3) & 1) * 256 + (t & 31) * 8 + (d & 7));
          if (which == 0) Qf[bh + a] = f2bf(v * 0.18033688f);
          else            Kf[bh + a] = f2bf(v);
        }
      }
    }
  }
}

// ---------------- causal flash attention: LDS-free, fragment-ordered operands ----------------
// Block = 32 q-rows x 2 independent waves (even/odd 64-wide KV tiles). All K/V/Q
// fragment loads are coalesced global_load_dwordx4 (base + lane*16B), L2-served.
// No LDS staging, no barriers in the main loop -> residency capped by VGPR, not LDS.
// Tiny online-softmax merge of the two wave-partials via a 9KB LDS buffer at the end.
__global__ __launch_bounds__(128) void k_attn(const unsigned short* __restrict__ Qf,
                                              const unsigned short* __restrict__ Kf,
                                              const unsigned short* __restrict__ Vf,
                                              unsigned short* __restrict__ Y) {
  __shared__ float ex[64 * 33];     // wave-1 partial O (+1-pad rotation)
  __shared__ float exml[128];       // wave-1 m,l
  int tid = threadIdx.x;            // 0..127
  int jx = blockIdx.x;              // 0..2047
  int j = 63 - (jx >> 5);           // 32-row q-subtile, biggest jobs first
  int bh = jx & 31;
  int wid = tid >> 6, lane = tid & 63;
  int l31 = lane & 31, h = lane >> 5;
  int q0 = j * 32;
  int qrow = q0 + l31;
  int tmax = j >> 1;                // last 64-wide KV tile index

  const unsigned short* Qp = Qf + (size_t)bh * TT * DD;
  const unsigned short* Kp = Kf + (size_t)bh * TT * DD;
  const unsigned short* Vp = Vf + (size_t)bh * TT * DD;

  // Q fragments: row-group j, coalesced
  short8 qf[4];
#pragma unroll
  for (int m = 0; m < 4; ++m)
    qf[m] = *(const short8*)(Qp + (size_t)(j * 4 + m) * 512 + lane * 8);

  f32x16 zv;
#pragma unroll
  for (int r = 0; r < 16; ++r) zv[r] = 0.0f;
  f32x16 po[2];
  po[0] = zv; po[1] = zv;
  float mrun = -1e30f, lrun = 0.0f;

  for (int t = wid; t <= tmax; t += 2) {
    int kvb = t * 64;

    // K fragments (coalesced) -> QK^T
    short8 kf[2][4];
#pragma unroll
    for (int t32 = 0; t32 < 2; ++t32)
#pragma unroll
      for (int m = 0; m < 4; ++m)
        kf[t32][m] = *(const short8*)(Kp + (size_t)((t * 2 + t32) * 4 + m) * 512 + lane * 8);

    f32x16 st[2];
    __builtin_amdgcn_s_setprio(1);
#pragma unroll
    for (int t32 = 0; t32 < 2; ++t32) {
      st[t32] = __builtin_amdgcn_mfma_f32_32x32x16_bf16(kf[t32][0], qf[0], zv, 0, 0, 0);
#pragma unroll
      for (int m = 1; m < 4; ++m)
        st[t32] = __builtin_amdgcn_mfma_f32_32x32x16_bf16(kf[t32][m], qf[m], st[t32], 0, 0, 0);
    }
    __builtin_amdgcn_s_setprio(0);

    // V fragments (coalesced) -- issue now, consumed after softmax
    short8 vf[2][4];
#pragma unroll
    for (int dt = 0; dt < 2; ++dt)
#pragma unroll
      for (int g = 0; g < 4; ++g)
        vf[dt][g] = *(const short8*)(Vp + (size_t)((t * 2 + dt) * 4 + g) * 512 + lane * 8);

    if (kvb + 63 > q0) {              // diagonal tiles: causal mask
#pragma unroll
      for (int t32 = 0; t32 < 2; ++t32)
#pragma unroll
        for (int r = 0; r < 16; ++r) {
          int kvg = kvb + t32 * 32 + (r & 3) + 8 * (r >> 2) + 4 * h;
          if (kvg > qrow) st[t32][r] = -1e30f;
        }
    }

    // row max: v_max3 tree over 32 values, then cross-half
    float A = st[0][0], B = st[0][1], C = st[0][2], Dv = st[0][3];
#pragma unroll
    for (int r = 4; r < 16; r += 4) {
      A = fmax3(A, st[0][r], st[0][r + 1]);
      B = fmax3(B, st[0][r + 2], st[0][r + 3]);
      C = fmax3(C, st[1][r - 4], st[1][r - 3]);
      Dv = fmax3(Dv, st[1][r - 2], st[1][r - 1]);
    }
    C = fmax3(C, st[1][12], st[1][13]);
    Dv = fmax3(Dv, st[1][14], st[1][15]);
    float mx = fmaxf(fmax3(A, B, C), Dv);
    mx = fmaxf(mx, __shfl_xor(mx, 32));

    if (__any(mx - mrun > 8.0f)) {    // defer-max, log2 units
      float mnew = fmaxf(mrun, mx);
      float alpha = fexp2(mrun - mnew);
      lrun *= alpha;
#pragma unroll
      for (int dt = 0; dt < 2; ++dt)
#pragma unroll
        for (int r = 0; r < 16; ++r) po[dt][r] *= alpha;
      mrun = mnew;
    }

    float sum = 0.0f;
#pragma unroll
    for (int t32 = 0; t32 < 2; ++t32)
#pragma unroll
      for (int r = 0; r < 16; ++r) {
        float p = fexp2(st[t32][r] - mrun);
        st[t32][r] = p;
        sum += p;
      }
    sum += __shfl_xor(sum, 32);
    lrun += sum;

    // P -> bf16 B-fragments via cvt_pk + permlane32_swap
    short8 pf[4];
#pragma unroll
    for (int g = 0; g < 4; ++g) {
      int t32 = g >> 1, r0 = (g & 1) * 8;
      int a = cvtpk(st[t32][r0 + 0], st[t32][r0 + 1]);
      int b = cvtpk(st[t32][r0 + 4], st[t32][r0 + 5]);
      plswap(a, b);
      int c = cvtpk(st[t32][r0 + 2], st[t32][r0 + 3]);
      int d = cvtpk(st[t32][r0 + 6], st[t32][r0 + 7]);
      plswap(c, d);
      union { int w[4]; short8 s; } un;
      un.w[0] = a; un.w[1] = c; un.w[2] = b; un.w[3] = d;
      pf[g] = un.s;
    }

    // O^T += V^T . P
    __builtin_amdgcn_s_setprio(1);
#pragma unroll
    for (int dt = 0; dt < 2; ++dt)
#pragma unroll
      for (int g = 0; g < 4; ++g)
        po[dt] = __builtin_amdgcn_mfma_f32_32x32x16_bf16(vf[dt][g], pf[g], po[dt], 0, 0, 0);
    __builtin_amdgcn_s_setprio(0);
  }

  // merge the two wave-partials via LDS
  __syncthreads();
  if (wid == 1) {
#pragma unroll
    for (int dt = 0; dt < 2; ++dt)
#pragma unroll
      for (int r = 0; r < 16; ++r) ex[lane * 33 + dt * 16 + r] = po[dt][r];
    exml[lane] = mrun;
    exml[64 + lane] = lrun;
  }
  __syncthreads();
  if (wid == 0) {
    float m1 = exml[lane], l1 = exml[64 + lane];
    float M = fmaxf(mrun, m1);
    float a0 = fexp2(mrun - M), a1 = fexp2(m1 - M);
    float inv = 1.0f / (lrun * a0 + l1 * a1);
    a0 *= inv; a1 *= inv;
    int b = bh >> 4, hh = bh & 15;
    unsigned short* yp = Y + ((size_t)(b * TT + qrow)) * CCH + hh * DD;
#pragma unroll
    for (int dt = 0; dt < 2; ++dt)
#pragma unroll
      for (int r = 0; r < 16; r += 2) {
        int d = dt * 32 + (r & 3) + 8 * (r >> 2) + 4 * h;
        float v0 = po[dt][r]     * a0 + ex[lane * 33 + dt * 16 + r]     * a1;
        float v1 = po[dt][r + 1] * a0 + ex[lane * 33 + dt * 16 + r + 1] * a1;
        *(int*)(yp + d) = cvtpk(v0, v1);
      }
  }
}

// ---------------- proj GEMM (m97 pattern): Yb bf16 @ Wt_proj bf16 + bias -> f32 out ----------------
__global__ __launch_bounds__(256) void k_proj_gemm(const unsigned short* __restrict__ Yb,
                                                   const unsigned short* __restrict__ Wt,
                                                   const float* __restrict__ bias,
                                                   float* __restrict__ Out) {
  __shared__ __align__(16) unsigned short As[128 * 32];
  __shared__ __align__(16) unsigned short Bs[128 * 32];
  int tid = threadIdx.x;
  int mb = blockIdx.x * 128;
  int nb = blockIdx.y * 128;
  int wid = tid >> 6, lane = tid & 63;
  int wr = (wid >> 1) * 64, wc = (wid & 1) * 64;
  int l15 = lane & 15, l4 = lane >> 4;
  int l16 = lane >> 2, lc = (lane & 3) * 8;
  f32x4 acc[4][4];
#pragma unroll
  for (int a = 0; a < 4; ++a)
#pragma unroll
    for (int b = 0; b < 4; ++b)
#pragma unroll
      for (int j = 0; j < 4; ++j) acc[a][b][j] = 0.0f;

  for (int kb = 0; kb < CCH; kb += 32) {
#pragma unroll
    for (int i = 0; i < 2; ++i) {
      int arow = wid * 32 + i * 16;
      gload_lds16(Yb + (size_t)(mb + arow + l16) * CCH + kb + lc, &As[arow * 32]);
      gload_lds16(Wt + (size_t)(nb + arow + l16) * CCH + kb + lc, &Bs[arow * 32]);
    }
    __syncthreads();
    short8 af[4], bfr[4];
#pragma unroll
    for (int mt = 0; mt < 4; ++mt) af[mt] = *(const short8*)(&As[(wr + mt * 16 + l15) * 32 + l4 * 8]);
#pragma unroll
    for (int nt = 0; nt < 4; ++nt) bfr[nt] = *(const short8*)(&Bs[(wc + nt * 16 + l15) * 32 + l4 * 8]);
#pragma unroll
    for (int mt = 0; mt < 4; ++mt)
#pragma unroll
      for (int nt = 0; nt < 4; ++nt)
        acc[mt][nt] = __builtin_amdgcn_mfma_f32_16x16x32_bf16(af[mt], bfr[nt], acc[mt][nt], 0, 0, 0);
    __syncthreads();
  }

#pragma unroll
  for (int mt = 0; mt < 4; ++mt) {
#pragma unroll
    for (int nt = 0; nt < 4; ++nt) {
      int gcol = nb + wc + nt * 16 + l15;
      float bv = bias[gcol];
#pragma unroll
      for (int j = 0; j < 4; ++j) {
        int grow = mb + wr + mt * 16 + l4 * 4 + j;
        Out[(size_t)grow * CCH + gcol] = acc[mt][nt][j] + bv;
      }
    }
  }
}

extern "C" void kernel_launch(void* const* d_in, const int* in_sizes, int n_in,
                              void* d_out, int out_size, void* d_ws, size_t ws_size,
                              hipStream_t stream) {
  const float* x      = (const float*)d_in[0];
  const float* W_qkv  = (const float*)d_in[1];
  const float* b_qkv  = (const float*)d_in[2];
  const float* W_proj = (const float*)d_in[3];
  const float* b_proj = (const float*)d_in[4];
  float* out = (float*)d_out;

  char* ws = (char*)d_ws;
  size_t off = 0;
  unsigned short* Wt_qkv  = (unsigned short*)(ws + off); off += (size_t)N3 * CCH * 2;   // 6.3 MB
  unsigned short* Wt_proj = (unsigned short*)(ws + off); off += (size_t)CCH * CCH * 2;  // 2.1 MB
  unsigned short* Xb      = (unsigned short*)(ws + off); off += (size_t)BT * CCH * 2;   // 8.4 MB
  unsigned short* Qfb     = (unsigned short*)(ws + off); off += (size_t)BT * CCH * 2;   // 8.4 MB
  unsigned short* Kfb     = (unsigned short*)(ws + off); off += (size_t)BT * CCH * 2;   // 8.4 MB
  unsigned short* Vfb     = (unsigned short*)(ws + off); off += (size_t)BT * CCH * 2;   // 8.4 MB
  unsigned short* Yb      = (unsigned short*)(ws + off); off += (size_t)BT * CCH * 2;   // 8.4 MB

  k_convert<<<dim3(BT * CCH / 8 / 256), 256, 0, stream>>>(x, Xb, BT * CCH / 8);
  k_transpose_cvt<<<dim3(N3 / 32, CCH / 32), 256, 0, stream>>>(W_qkv, Wt_qkv, CCH, N3);
  k_transpose_cvt<<<dim3(CCH / 32, CCH / 32), 256, 0, stream>>>(W_proj, Wt_proj, CCH, CCH);
  k_qkv_gemm<<<dim3(BT / 128, N3 / 128), 256, 0, stream>>>(Xb, Wt_qkv, b_qkv, Qfb, Kfb, Vfb);
  k_attn<<<dim3(2048), 128, 0, stream>>>(Qfb, Kfb, Vfb, Yb);
  k_proj_gemm<<<dim3(BT / 128, CCH / 128), 256, 0, stream>>>(Yb, Wt_proj, b_proj, out);
}